// Round 4
// baseline (233.339 us; speedup 1.0000x reference)
//
#include <hip/hip_runtime.h>
#include <math.h>
#include <stdint.h>

// RelPositionMultiheadAttention (Transformer-XL style).
// L=2048, N=4, E=256, H=4, D=64.
//   1) proj_gemm<0,4>: qkv = x @ in_proj_w.T + b  (fp16 MFMA), fused epilogue
//      -> qu=(q*s+u), qv=(q*s+v), K as [bh][i][d] fp16 ; V^T [bh][d][j] fp16
//   2) proj_gemm<1,1>: p = pos_emb @ pos_w.T      -> pB [h][n][d] fp16
//   3) attn_mfma: fused flash attention, fp16 MFMA, rel-shift via banded BD^T
//   4) proj_gemm<2,2>: out = attn @ out_proj_w.T + b (fp32 out)

typedef __attribute__((ext_vector_type(8))) _Float16 half8;
typedef __attribute__((ext_vector_type(4))) float f32x4;
typedef unsigned short u16;
typedef unsigned int u32;

namespace {
constexpr int L_SEQ  = 2048;
constexpr int NB     = 4;
constexpr int EMB    = 256;
constexpr int NH     = 4;
constexpr int HD     = 64;
constexpr int E3     = 768;
constexpr int M_ROWS = L_SEQ * NB;     // 8192
constexpr int P_ROWS = 2 * L_SEQ - 1;  // 4095
}

__device__ __forceinline__ u16 f2h(float x) {
    _Float16 h = (_Float16)x;
    return __builtin_bit_cast(u16, h);
}
__device__ __forceinline__ u32 pk2(float a, float b) {
    return (u32)f2h(a) | ((u32)f2h(b) << 16);
}

// ---------------------------------------------------------------------------
// proj_gemm<MODE,MSUB>: C(M,N) = A(M,256) @ W(N,256)^T (+bias), fp16 MFMA.
// Block: 4 waves; per block ONE 64-col n-tile, MSUB 64-row m-subtiles.
// W staged fp32->fp16 once into swizzled LDS. A fragments 2-deep pipelined.
// Epilogue layout-transposes go through LDS -> fully coalesced 128B stores.
// D layout (verified): col=lane&15 -> m, row=(lane>>4)*4+reg -> n.
// ---------------------------------------------------------------------------
template <int MODE, int MSUB>
__global__ __launch_bounds__(256, 2) void proj_gemm(
        const void* __restrict__ Ap, const float* __restrict__ W,
        const float* __restrict__ Wb,
        const float* __restrict__ u_bias, const float* __restrict__ v_bias,
        u16* __restrict__ quB, u16* __restrict__ qvB,
        u16* __restrict__ kB,  u16* __restrict__ vtB,
        u16* __restrict__ o16, float* __restrict__ outf) {
    constexpr int NT   = (MODE == 0) ? 12 : 4;
    constexpr int SCRN = (MODE == 0) ? (4 * 64 * 72) : (MODE == 1 ? 64 * 72 : 8);
    __shared__ __align__(16) u16 ws[64 * 256];   // 32 KB swizzled W [n][k]
    __shared__ __align__(16) u16 scr[SCRN];      // epilogue transpose scratch

    const int t    = threadIdx.x;
    const int lane = t & 63;
    const int w    = t >> 6;
    const int il   = lane & 15;
    const int g    = lane >> 4;

    // XCD-chunked bijective swizzle; logical is m-major so one XCD's blocks
    // share A rows in its L2.
    const int qq = gridDim.x >> 3;
    const int logical = (blockIdx.x & 7) * qq + (blockIdx.x >> 3);
    const int mg = logical / NT, nt = logical % NT;
    const int n0 = nt * 64;

    half8 bf[2][8];
    float4 ra[2][8], rb[2][8];

    auto issueA = [&](int s, int p) {
        const int m_ = (mg * MSUB + s) * 64 + w * 16 + il;
        if constexpr (MODE == 2) {
            const u16* ar = (const u16*)Ap + (size_t)m_ * 256;
            #pragma unroll
            for (int c = 0; c < 8; ++c)
                bf[p][c] = *(const half8*)&ar[c * 32 + g * 8];
        } else {
            const int mld = (MODE == 1 && m_ > P_ROWS - 1) ? (P_ROWS - 1) : m_;
            const float* ar = (const float*)Ap + (size_t)mld * 256;
            #pragma unroll
            for (int c = 0; c < 8; ++c) {
                ra[p][c] = *(const float4*)&ar[c * 32 + g * 8];
                rb[p][c] = *(const float4*)&ar[c * 32 + g * 8 + 4];
            }
        }
    };
    auto packA = [&](int p) {
        if constexpr (MODE != 2) {
            #pragma unroll
            for (int c = 0; c < 8; ++c) {
                uint4 pk = make_uint4(pk2(ra[p][c].x, ra[p][c].y),
                                      pk2(ra[p][c].z, ra[p][c].w),
                                      pk2(rb[p][c].x, rb[p][c].y),
                                      pk2(rb[p][c].z, rb[p][c].w));
                bf[p][c] = __builtin_bit_cast(half8, pk);
            }
        }
    };

    issueA(0, 0);
    // ---- stage W tile once: 64 n-rows x 256 k, fp32->fp16, swizzled ----
    {
        const int kc = (t & 31) * 8;
        const int rb_ = t >> 5;
        #pragma unroll
        for (int rr = 0; rr < 8; ++rr) {
            const int row = rb_ * 8 + rr;
            const float* wr = &W[(size_t)(n0 + row) * 256 + kc];
            float4 f0 = *(const float4*)&wr[0];
            float4 f1 = *(const float4*)&wr[4];
            uint4 pk = make_uint4(pk2(f0.x, f0.y), pk2(f0.z, f0.w),
                                  pk2(f1.x, f1.y), pk2(f1.z, f1.w));
            *(uint4*)((char*)ws + row * 512 + ((kc * 2) ^ ((row & 7) << 4))) = pk;
        }
    }
    packA(0);
    __syncthreads();

    const int seg = (MODE == 0) ? (nt >> 2) : 0;
    const int h   = (MODE == 0) ? (nt & 3) : nt;

    #pragma unroll
    for (int s = 0; s < MSUB; ++s) {
        if (s + 1 < MSUB) issueA(s + 1, (s + 1) & 1);

        // ---- 32 MFMAs ----
        f32x4 acc[4] = {};
        #pragma unroll
        for (int c = 0; c < 8; ++c) {
            #pragma unroll
            for (int jt = 0; jt < 4; ++jt) {
                const int row = jt * 16 + il;
                half8 af = *(const half8*)((const char*)ws + row * 512 +
                                           ((c * 64 + g * 16) ^ ((row & 7) << 4)));
                acc[jt] = __builtin_amdgcn_mfma_f32_16x16x32_f16(af, bf[s & 1][c], acc[jt], 0, 0, 0);
            }
        }

        float av[4][4];
        #pragma unroll
        for (int jt = 0; jt < 4; ++jt)
            #pragma unroll
            for (int r = 0; r < 4; ++r)
                av[jt][r] = acc[jt][r] +
                    ((MODE != 1) ? Wb[n0 + jt * 16 + g * 4 + r] : 0.f);

        const int s64  = (mg * MSUB + s) * 64;
        const int mloc = w * 16 + il;

        if constexpr (MODE == 0) {
            if (seg == 0) {
                const int i0g = s64 >> 2;
                // pass 1: qu
                __syncthreads();
                #pragma unroll
                for (int jt = 0; jt < 4; ++jt) {
                    const int d0 = jt * 16 + g * 4;
                    float uu[4];
                    #pragma unroll
                    for (int r = 0; r < 4; ++r)
                        uu[r] = av[jt][r] * 0.125f + u_bias[h * 64 + d0 + r];
                    *(uint2*)&scr[mloc * 72 + d0] = make_uint2(pk2(uu[0], uu[1]), pk2(uu[2], uu[3]));
                }
                __syncthreads();
                {
                    const int b_ = t >> 6, iL = (t >> 2) & 15, dq = (t & 3) * 16;
                    uint4 v0 = *(const uint4*)&scr[(iL * 4 + b_) * 72 + dq];
                    uint4 v1 = *(const uint4*)&scr[(iL * 4 + b_) * 72 + dq + 8];
                    u16* dst = &quB[(((size_t)(b_ * 4 + h)) * 2048 + i0g + iL) * 64 + dq];
                    *(uint4*)&dst[0] = v0; *(uint4*)&dst[8] = v1;
                }
                // pass 2: qv
                __syncthreads();
                #pragma unroll
                for (int jt = 0; jt < 4; ++jt) {
                    const int d0 = jt * 16 + g * 4;
                    float vv[4];
                    #pragma unroll
                    for (int r = 0; r < 4; ++r)
                        vv[r] = av[jt][r] * 0.125f + v_bias[h * 64 + d0 + r];
                    *(uint2*)&scr[mloc * 72 + d0] = make_uint2(pk2(vv[0], vv[1]), pk2(vv[2], vv[3]));
                }
                __syncthreads();
                {
                    const int b_ = t >> 6, iL = (t >> 2) & 15, dq = (t & 3) * 16;
                    uint4 v0 = *(const uint4*)&scr[(iL * 4 + b_) * 72 + dq];
                    uint4 v1 = *(const uint4*)&scr[(iL * 4 + b_) * 72 + dq + 8];
                    u16* dst = &qvB[(((size_t)(b_ * 4 + h)) * 2048 + i0g + iL) * 64 + dq];
                    *(uint4*)&dst[0] = v0; *(uint4*)&dst[8] = v1;
                }
            } else if (seg == 1) {
                const int i0g = s64 >> 2;
                __syncthreads();
                #pragma unroll
                for (int jt = 0; jt < 4; ++jt) {
                    const int d0 = jt * 16 + g * 4;
                    *(uint2*)&scr[mloc * 72 + d0] =
                        make_uint2(pk2(av[jt][0], av[jt][1]), pk2(av[jt][2], av[jt][3]));
                }
                __syncthreads();
                {
                    const int b_ = t >> 6, iL = (t >> 2) & 15, dq = (t & 3) * 16;
                    uint4 v0 = *(const uint4*)&scr[(iL * 4 + b_) * 72 + dq];
                    uint4 v1 = *(const uint4*)&scr[(iL * 4 + b_) * 72 + dq + 8];
                    u16* dst = &kB[(((size_t)(b_ * 4 + h)) * 2048 + i0g + iL) * 64 + dq];
                    *(uint4*)&dst[0] = v0; *(uint4*)&dst[8] = v1;
                }
            } else {
                // seg V: accumulate [b][j_loc][d] tile across subtiles (no barrier)
                const int b_ = il & 3;
                const int jl = s * 16 + w * 4 + (il >> 2);
                #pragma unroll
                for (int jt = 0; jt < 4; ++jt) {
                    const int d0 = jt * 16 + g * 4;
                    *(uint2*)&scr[(b_ * 64 + jl) * 72 + d0] =
                        make_uint2(pk2(av[jt][0], av[jt][1]), pk2(av[jt][2], av[jt][3]));
                }
            }
        } else if constexpr (MODE == 1) {
            __syncthreads();
            #pragma unroll
            for (int jt = 0; jt < 4; ++jt) {
                const int d0 = jt * 16 + g * 4;
                *(uint2*)&scr[mloc * 72 + d0] =
                    make_uint2(pk2(av[jt][0], av[jt][1]), pk2(av[jt][2], av[jt][3]));
            }
            __syncthreads();
            {
                const int nL = t >> 2, dq = (t & 3) * 16;
                const int mrow = s64 + nL;
                if (mrow < P_ROWS) {
                    uint4 v0 = *(const uint4*)&scr[nL * 72 + dq];
                    uint4 v1 = *(const uint4*)&scr[nL * 72 + dq + 8];
                    u16* dst = &o16[((size_t)h * P_ROWS + mrow) * 64 + dq];
                    *(uint4*)&dst[0] = v0; *(uint4*)&dst[8] = v1;
                }
            }
        } else {
            const int m_ = s64 + mloc;
            float* orow = &outf[(size_t)m_ * 256 + n0];
            #pragma unroll
            for (int jt = 0; jt < 4; ++jt)
                *(float4*)&orow[jt * 16 + g * 4] =
                    make_float4(av[jt][0], av[jt][1], av[jt][2], av[jt][3]);
        }

        if (s + 1 < MSUB) packA((s + 1) & 1);
    }

    // ---- seg V flush: coalesced 128B-row stores of the 64-j tile ----
    if constexpr (MODE == 0) {
        if (seg == 2) {
            __syncthreads();
            const int jbase = mg * 64;   // MSUB==4 -> block covers 64 j
            #pragma unroll
            for (int b_ = 0; b_ < 4; ++b_) {
                const int d = t >> 2, jc = (t & 3) * 16;
                u32 pkx[8];
                #pragma unroll
                for (int z = 0; z < 8; ++z)
                    pkx[z] = (u32)scr[(b_ * 64 + jc + 2 * z) * 72 + d] |
                             ((u32)scr[(b_ * 64 + jc + 2 * z + 1) * 72 + d] << 16);
                u16* dst = &vtB[(((size_t)(b_ * 4 + h)) * 64 + d) * 2048 + jbase + jc];
                *(uint4*)&dst[0] = make_uint4(pkx[0], pkx[1], pkx[2], pkx[3]);
                *(uint4*)&dst[8] = make_uint4(pkx[4], pkx[5], pkx[6], pkx[7]);
            }
        }
    }
}

// ---------------------------------------------------------------------------
// Fused rel-pos flash attention, fp16 MFMA, all-transposed layout.
// grid 512 (XCD-swizzled -> (bh, i0)), block 256 = 4 waves, 64 q-rows/block.
// S^T = mfma(K, Qu); BD^T = mfma(P, Qv) -> banded LDS; Out^T = mfma(V^T, prob).
// T14 async staging: next tile's global loads issued before compute, LDS
// writes happen at the top of the next iteration.
// ---------------------------------------------------------------------------
__global__ __launch_bounds__(256, 2) void attn_mfma(
        const u16* __restrict__ quB, const u16* __restrict__ qvB,
        const u16* __restrict__ kB,  const u16* __restrict__ vtB,
        const u16* __restrict__ pB,  u16* __restrict__ attn_out) {
    __shared__ __align__(16) u16   k_s[64 * 64];      // [j][d]   8 KB
    __shared__ __align__(16) u16   v_s[64 * 64];      // [d][j]   8 KB
    __shared__ __align__(16) u16   p_s[128 * 64];     // [r][d]  16 KB
    __shared__ __align__(16) float bd_s[4][16 * 84];  // per-wave [il][rr] 21 KB
    __shared__ __align__(16) u16   prob_s[4][16 * 64];// per-wave [il][j]  8 KB

    const int t    = threadIdx.x;
    const int lane = t & 63;
    const int w    = t >> 6;
    const int il   = lane & 15;
    const int g    = lane >> 4;

    const int logical = ((blockIdx.x & 7) << 6) + (blockIdx.x >> 3);
    const int bh = logical >> 5;
    const int i0 = (logical & 31) * 64;
    const int b  = bh >> 2, h = bh & 3;

    half8 qu_f[2], qv_f[2];
    {
        const size_t qrow = ((size_t)bh * L_SEQ + i0 + w * 16 + il) * HD;
        qu_f[0] = *(const half8*)&quB[qrow + g * 8];
        qu_f[1] = *(const half8*)&quB[qrow + 32 + g * 8];
        qv_f[0] = *(const half8*)&qvB[qrow + g * 8];
        qv_f[1] = *(const half8*)&qvB[qrow + 32 + g * 8];
    }

    const int r0w = 48 - 16 * w;
    int krd[4][2], prd[5][2], pbrd[2], pwr[4];
    #pragma unroll
    for (int x4 = 0; x4 < 4; ++x4)
        #pragma unroll
        for (int c = 0; c < 2; ++c) {
            int row = x4 * 16 + il;
            krd[x4][c] = row * 128 + ((c * 64 + g * 16) ^ ((row & 7) << 4));
        }
    #pragma unroll
    for (int rt = 0; rt < 5; ++rt)
        #pragma unroll
        for (int c = 0; c < 2; ++c) {
            int row = r0w + rt * 16 + il;
            prd[rt][c] = row * 128 + ((c * 64 + g * 16) ^ ((row & 7) << 4));
        }
    #pragma unroll
    for (int c = 0; c < 2; ++c)
        pbrd[c] = il * 128 + ((c * 64 + g * 16) ^ ((il & 7) << 4));
    #pragma unroll
    for (int jt = 0; jt < 4; ++jt)
        pwr[jt] = il * 128 + (((jt * 16 + g * 4) * 2) ^ ((il & 7) << 4));
    const int bdwr = il * 84 + g * 4;
    const int bdrd = il * 83 + 15 + g * 4;

    // staging: per-thread slots (kt-invariant dests, per-kt sources)
    const int rw = t >> 3, a8 = t & 7;
    int kds[2], vds[2], pds[4];
    #pragma unroll
    for (int kr = 0; kr < 2; ++kr) {
        const int j = kr * 32 + rw;
        kds[kr] = j * 128 + ((a8 * 16) ^ ((j & 7) << 4));
    }
    #pragma unroll
    for (int vr = 0; vr < 2; ++vr) {
        const int d = vr * 32 + rw;
        vds[vr] = d * 128 + ((a8 * 16) ^ ((d & 7) << 4));
    }
    #pragma unroll
    for (int pr = 0; pr < 4; ++pr) {
        const int r = pr * 32 + rw;
        pds[pr] = r * 128 + ((a8 * 16) ^ ((r & 7) << 4));
    }
    uint4 kreg[2], vreg[2], preg[4];
    auto stageLoad = [&](int kt) {
        #pragma unroll
        for (int kr = 0; kr < 2; ++kr)
            kreg[kr] = *(const uint4*)&kB[((size_t)bh * 2048 + kt * 64 + kr * 32 + rw) * 64 + a8 * 8];
        #pragma unroll
        for (int vr = 0; vr < 2; ++vr)
            vreg[vr] = *(const uint4*)&vtB[((size_t)bh * 64 + vr * 32 + rw) * 2048 + (size_t)kt * 64 + a8 * 8];
        #pragma unroll
        for (int pr = 0; pr < 4; ++pr) {
            int n = 1984 - i0 + kt * 64 + pr * 32 + rw;
            n = n > (P_ROWS - 1) ? (P_ROWS - 1) : n;
            preg[pr] = *(const uint4*)&pB[((size_t)h * P_ROWS + n) * 64 + a8 * 8];
        }
    };

    f32x4 outacc[4] = {};
    float m_run = -INFINITY, l_run = 0.f;

    stageLoad(0);
    for (int kt = 0; kt < 32; ++kt) {
        __syncthreads();   // previous tile's consumers done
        #pragma unroll
        for (int kr = 0; kr < 2; ++kr)
            *(uint4*)((char*)k_s + kds[kr]) = kreg[kr];
        #pragma unroll
        for (int vr = 0; vr < 2; ++vr)
            *(uint4*)((char*)v_s + vds[vr]) = vreg[vr];
        #pragma unroll
        for (int pr = 0; pr < 4; ++pr)
            *(uint4*)((char*)p_s + pds[pr]) = preg[pr];
        if (kt < 31) stageLoad(kt + 1);   // in flight across the compute phase
        __syncthreads();

        // ---- BD^T band ----
        __builtin_amdgcn_s_setprio(1);
        #pragma unroll
        for (int rt = 0; rt < 5; ++rt) {
            f32x4 acc = {};
            #pragma unroll
            for (int c = 0; c < 2; ++c) {
                half8 a = *(const half8*)((const char*)p_s + prd[rt][c]);
                acc = __builtin_amdgcn_mfma_f32_16x16x32_f16(a, qv_f[c], acc, 0, 0, 0);
            }
            *(f32x4*)&bd_s[w][bdwr + rt * 16] = acc;
        }
        __builtin_amdgcn_s_setprio(0);

        // ---- AC (S^T) + rel-shift combine ----
        float sreg[16];
        __builtin_amdgcn_s_setprio(1);
        #pragma unroll
        for (int jt = 0; jt < 4; ++jt) {
            f32x4 acc = {};
            #pragma unroll
            for (int c = 0; c < 2; ++c) {
                half8 a = *(const half8*)((const char*)k_s + krd[jt][c]);
                acc = __builtin_amdgcn_mfma_f32_16x16x32_f16(a, qu_f[c], acc, 0, 0, 0);
            }
            #pragma unroll
            for (int tt = 0; tt < 4; ++tt)
                sreg[jt * 4 + tt] = acc[tt] + bd_s[w][bdrd + jt * 16 + tt];
        }
        __builtin_amdgcn_s_setprio(0);

        // ---- online softmax ----
        float mx = sreg[0];
        #pragma unroll
        for (int z = 1; z < 16; ++z) mx = fmaxf(mx, sreg[z]);
        mx = fmaxf(mx, __shfl_xor(mx, 16));
        mx = fmaxf(mx, __shfl_xor(mx, 32));
        const float m_new = fmaxf(m_run, mx);
        const float corr = __expf(m_run - m_new);
        float lsum = 0.f;
        #pragma unroll
        for (int z = 0; z < 16; ++z) { sreg[z] = __expf(sreg[z] - m_new); lsum += sreg[z]; }
        lsum += __shfl_xor(lsum, 16);
        lsum += __shfl_xor(lsum, 32);
        l_run = l_run * corr + lsum;
        m_run = m_new;
        #pragma unroll
        for (int dt = 0; dt < 4; ++dt) outacc[dt] *= corr;

        // ---- pack probabilities ----
        #pragma unroll
        for (int jt = 0; jt < 4; ++jt) {
            u32 lo = pk2(sreg[jt * 4 + 0], sreg[jt * 4 + 1]);
            u32 hi = pk2(sreg[jt * 4 + 2], sreg[jt * 4 + 3]);
            *(uint2*)((char*)&prob_s[w][0] + pwr[jt]) = make_uint2(lo, hi);
        }

        // ---- PV ----
        half8 pfrag[2];
        #pragma unroll
        for (int c = 0; c < 2; ++c)
            pfrag[c] = *(const half8*)((const char*)&prob_s[w][0] + pbrd[c]);
        __builtin_amdgcn_s_setprio(1);
        #pragma unroll
        for (int dt = 0; dt < 4; ++dt) {
            #pragma unroll
            for (int c = 0; c < 2; ++c) {
                half8 a = *(const half8*)((const char*)v_s + krd[dt][c]);
                outacc[dt] = __builtin_amdgcn_mfma_f32_16x16x32_f16(a, pfrag[c], outacc[dt], 0, 0, 0);
            }
        }
        __builtin_amdgcn_s_setprio(0);
    }

    // ---- epilogue: fp16 [m][e] ----
    const float inv = 1.f / l_run;
    const int m = (i0 + w * 16 + il) * NB + b;
    u16* orow = &attn_out[(size_t)m * EMB + h * HD];
    #pragma unroll
    for (int dt = 0; dt < 4; ++dt) {
        u32 lo = pk2(outacc[dt][0] * inv, outacc[dt][1] * inv);
        u32 hi = pk2(outacc[dt][2] * inv, outacc[dt][3] * inv);
        *(uint2*)&orow[dt * 16 + g * 4] = make_uint2(lo, hi);
    }
}

// ---------------------------------------------------------------------------
extern "C" void kernel_launch(void* const* d_in, const int* in_sizes, int n_in,
                              void* d_out, int out_size, void* d_ws, size_t ws_size,
                              hipStream_t stream) {
    const float* x        = (const float*)d_in[0];
    const float* pos_emb  = (const float*)d_in[1];
    const float* in_w     = (const float*)d_in[2];
    const float* in_b     = (const float*)d_in[3];
    const float* pos_w    = (const float*)d_in[4];
    const float* u_bias   = (const float*)d_in[5];
    const float* v_bias   = (const float*)d_in[6];
    const float* out_w    = (const float*)d_in[7];
    const float* out_b    = (const float*)d_in[8];
    float* out = (float*)d_out;

    // fp16 workspace (~23 MB)
    u16* quB   = (u16*)d_ws;
    u16* qvB   = quB + (size_t)16 * L_SEQ * HD;
    u16* kB    = qvB + (size_t)16 * L_SEQ * HD;
    u16* vtB   = kB  + (size_t)16 * L_SEQ * HD;
    u16* pB    = vtB + (size_t)16 * L_SEQ * HD;
    u16* attnb = pB  + (size_t)NH * P_ROWS * HD;

    proj_gemm<0, 4><<<dim3(32 * 12), 256, 0, stream>>>(
        x, in_w, in_b, u_bias, v_bias, quB, qvB, kB, vtB, nullptr, nullptr);
    proj_gemm<1, 1><<<dim3(64 * 4), 256, 0, stream>>>(
        pos_emb, pos_w, nullptr, nullptr, nullptr,
        nullptr, nullptr, nullptr, nullptr, pB, nullptr);
    attn_mfma<<<dim3(512), 256, 0, stream>>>(quB, qvB, kB, vtB, pB, attnb);
    proj_gemm<2, 2><<<dim3(64 * 4), 256, 0, stream>>>(
        attnb, out_w, out_b, nullptr, nullptr,
        nullptr, nullptr, nullptr, nullptr, nullptr, out);
}

// Round 5
// 171.406 us; speedup vs baseline: 1.3613x; 1.3613x over previous
//
#include <hip/hip_runtime.h>
#include <math.h>
#include <stdint.h>

// RelPositionMultiheadAttention (Transformer-XL style).
// L=2048, N=4, E=256, H=4, D=64.
//   1) qkvpos_gemm: fused  qkv = x@in_proj_w.T+b  AND  p = pos_emb@pos_w.T
//      (fp16 MFMA, 16x16x32).  Epilogues write qu=(q*s+u), qv=(q*s+v), K as
//      [bh][i][d] fp16, V^T as [bh][d][j] fp16, P as [h][n][d] fp16.
//   2) attn_mfma: fused flash attention (verified round-3 version, untouched)
//   3) out_gemm: out = attn @ out_proj_w.T + b (fp32 out)

typedef __attribute__((ext_vector_type(8))) _Float16 half8;
typedef __attribute__((ext_vector_type(4))) float f32x4;
typedef unsigned short u16;
typedef unsigned int u32;

namespace {
constexpr int L_SEQ  = 2048;
constexpr int NB     = 4;
constexpr int EMB    = 256;
constexpr int NH     = 4;
constexpr int HD     = 64;
constexpr int P_ROWS = 2 * L_SEQ - 1;  // 4095
}

__device__ __forceinline__ u16 f2h(float x) {
    _Float16 h = (_Float16)x;
    return __builtin_bit_cast(u16, h);
}
__device__ __forceinline__ u32 pk2(float a, float b) {
    return (u32)f2h(a) | ((u32)f2h(b) << 16);
}

// ---------------------------------------------------------------------------
// Fused qkv + pos projection. Grid 896 = 768 (qkv: 64 mg x 12 nt) + 128
// (pos: 32 mg x 4 nt). Block: 4 waves; each wave owns 32 m-rows (2 sets of
// 16) so every LDS W-fragment read feeds TWO MFMAs. Epilogue transposes use
// per-wave private LDS scratch -> no barriers (V-transpose: one barrier).
// D layout (verified): col=lane&15 -> m, row=(lane>>4)*4+reg -> n.
// ---------------------------------------------------------------------------
__global__ __launch_bounds__(256, 2) void qkvpos_gemm(
        const float* __restrict__ x, const float* __restrict__ pos_emb,
        const float* __restrict__ in_w, const float* __restrict__ in_b,
        const float* __restrict__ pos_w,
        const float* __restrict__ u_bias, const float* __restrict__ v_bias,
        u16* __restrict__ quB, u16* __restrict__ qvB,
        u16* __restrict__ kB,  u16* __restrict__ vtB, u16* __restrict__ pB) {
    __shared__ __align__(16) u16 ws[64 * 256];   // 32 KB swizzled W [n][k]
    __shared__ __align__(16) u16 scr[128 * 72];  // 18 KB epilogue scratch

    const int t    = threadIdx.x;
    const int lane = t & 63;
    const int w    = t >> 6;
    const int il   = lane & 15;
    const int g    = lane >> 4;

    // XCD-chunked bijective swizzle (896 = 8 * 112); qkv logicals are
    // nt-minor so the 12 n-tiles sharing A rows land on one XCD's L2.
    const int logical = (blockIdx.x & 7) * 112 + (blockIdx.x >> 3);
    const bool isQKV = logical < 768;
    int mg, nt;
    const float *Ap, *W, *Wb;
    if (isQKV) { mg = logical / 12; nt = logical % 12; Ap = x;       W = in_w;  Wb = in_b; }
    else       { const int l2 = logical - 768;
                 mg = l2 >> 2;     nt = l2 & 3;      Ap = pos_emb; W = pos_w; Wb = nullptr; }
    const int m0 = mg * 128, n0 = nt * 64;

    // ---- stage W tile once: 64 n-rows x 256 k, fp32 -> fp16, swizzled ----
    {
        const int kc = (t & 31) * 8, rb_ = t >> 5;
        #pragma unroll
        for (int rr = 0; rr < 8; ++rr) {
            const int row = rb_ * 8 + rr;
            const float* wr = &W[(size_t)(n0 + row) * 256 + kc];
            float4 f0 = *(const float4*)&wr[0];
            float4 f1 = *(const float4*)&wr[4];
            *(uint4*)((char*)ws + row * 512 + ((kc * 2) ^ ((row & 7) << 4))) =
                make_uint4(pk2(f0.x, f0.y), pk2(f0.z, f0.w),
                           pk2(f1.x, f1.y), pk2(f1.z, f1.w));
        }
    }

    // ---- A fragments: two 16-row sets per wave (fp32 -> fp16 pack) ----
    half8 bf0[8], bf1[8];
    {
        int r0 = m0 + w * 32 + il;
        int r1 = r0 + 16;
        if (!isQKV) { r0 = r0 > 4094 ? 4094 : r0; r1 = r1 > 4094 ? 4094 : r1; }
        const float* a0 = Ap + (size_t)r0 * 256;
        const float* a1 = Ap + (size_t)r1 * 256;
        #pragma unroll
        for (int c = 0; c < 8; ++c) {
            float4 f0 = *(const float4*)&a0[c * 32 + g * 8];
            float4 f1 = *(const float4*)&a0[c * 32 + g * 8 + 4];
            bf0[c] = __builtin_bit_cast(half8,
                make_uint4(pk2(f0.x, f0.y), pk2(f0.z, f0.w),
                           pk2(f1.x, f1.y), pk2(f1.z, f1.w)));
            float4 h0 = *(const float4*)&a1[c * 32 + g * 8];
            float4 h1 = *(const float4*)&a1[c * 32 + g * 8 + 4];
            bf1[c] = __builtin_bit_cast(half8,
                make_uint4(pk2(h0.x, h0.y), pk2(h0.z, h0.w),
                           pk2(h1.x, h1.y), pk2(h1.z, h1.w)));
        }
    }
    __syncthreads();

    // ---- main loop: each af read feeds 2 MFMAs ----
    f32x4 acc0[4] = {}, acc1[4] = {};
    __builtin_amdgcn_s_setprio(1);
    #pragma unroll
    for (int c = 0; c < 8; ++c) {
        #pragma unroll
        for (int jt = 0; jt < 4; ++jt) {
            const int row = jt * 16 + il;
            half8 af = *(const half8*)((const char*)ws + row * 512 +
                                       ((c * 64 + g * 16) ^ ((row & 7) << 4)));
            acc0[jt] = __builtin_amdgcn_mfma_f32_16x16x32_f16(af, bf0[c], acc0[jt], 0, 0, 0);
            acc1[jt] = __builtin_amdgcn_mfma_f32_16x16x32_f16(af, bf1[c], acc1[jt], 0, 0, 0);
        }
    }
    __builtin_amdgcn_s_setprio(0);

    float av[2][4][4];
    #pragma unroll
    for (int jt = 0; jt < 4; ++jt)
        #pragma unroll
        for (int r = 0; r < 4; ++r) {
            const float bb = Wb ? Wb[n0 + jt * 16 + g * 4 + r] : 0.f;
            av[0][jt][r] = acc0[jt][r] + bb;
            av[1][jt][r] = acc1[jt][r] + bb;
        }

    // ---- epilogues (per-wave scratch; no barriers) ----
    u16* scrw = scr + w * (32 * 72);
    const int rrd  = lane >> 1;          // row 0..31 within wave tile
    const int base = (lane & 1) * 32;    // d half (32 elems = 64 B)

    auto waveStore = [&](u16* dstBase, int hh, float scale, const float* bias,
                         bool qkvLayout) {
        #pragma unroll
        for (int s = 0; s < 2; ++s)
            #pragma unroll
            for (int jt = 0; jt < 4; ++jt) {
                const int d0 = jt * 16 + g * 4;
                float v0 = av[s][jt][0] * scale, v1 = av[s][jt][1] * scale;
                float v2 = av[s][jt][2] * scale, v3 = av[s][jt][3] * scale;
                if (bias) {
                    v0 += bias[hh * 64 + d0 + 0]; v1 += bias[hh * 64 + d0 + 1];
                    v2 += bias[hh * 64 + d0 + 2]; v3 += bias[hh * 64 + d0 + 3];
                }
                *(uint2*)&scrw[(s * 16 + il) * 72 + d0] = make_uint2(pk2(v0, v1), pk2(v2, v3));
            }
        uint4 q0 = *(const uint4*)&scrw[rrd * 72 + base + 0];
        uint4 q1 = *(const uint4*)&scrw[rrd * 72 + base + 8];
        uint4 q2 = *(const uint4*)&scrw[rrd * 72 + base + 16];
        uint4 q3 = *(const uint4*)&scrw[rrd * 72 + base + 24];
        const int mglob = m0 + w * 32 + rrd;
        if (qkvLayout) {
            const int i = mglob >> 2, b = mglob & 3;
            u16* dp = dstBase + (((size_t)(b * 4 + hh)) * 2048 + i) * 64 + base;
            *(uint4*)&dp[0] = q0; *(uint4*)&dp[8] = q1;
            *(uint4*)&dp[16] = q2; *(uint4*)&dp[24] = q3;
        } else if (mglob < P_ROWS) {
            u16* dp = dstBase + ((size_t)hh * P_ROWS + mglob) * 64 + base;
            *(uint4*)&dp[0] = q0; *(uint4*)&dp[8] = q1;
            *(uint4*)&dp[16] = q2; *(uint4*)&dp[24] = q3;
        }
    };

    if (isQKV) {
        const int seg = nt >> 2, h = nt & 3;
        if (seg == 0) {
            waveStore(quB, h, 0.125f, u_bias, true);
            waveStore(qvB, h, 0.125f, v_bias, true);
        } else if (seg == 1) {
            waveStore(kB, h, 1.f, nullptr, true);
        } else {
            // V: block-wide transpose -> vtB [bh][d][j], j-span 32 per b
            #pragma unroll
            for (int s = 0; s < 2; ++s)
                #pragma unroll
                for (int jt = 0; jt < 4; ++jt)
                    *(uint2*)&scr[(w * 32 + s * 16 + il) * 72 + jt * 16 + g * 4] =
                        make_uint2(pk2(av[s][jt][0], av[s][jt][1]),
                                   pk2(av[s][jt][2], av[s][jt][3]));
            __syncthreads();
            const int b_ = w, d = lane;   // wave = batch, lane = head-dim
            u32 pkx[16];
            #pragma unroll
            for (int z = 0; z < 16; ++z)
                pkx[z] = (u32)scr[((2 * z) * 4 + b_) * 72 + d] |
                         ((u32)scr[((2 * z + 1) * 4 + b_) * 72 + d] << 16);
            u16* dp = vtB + (((size_t)(b_ * 4 + h)) * 64 + d) * 2048 + mg * 32;
            *(uint4*)&dp[0]  = make_uint4(pkx[0],  pkx[1],  pkx[2],  pkx[3]);
            *(uint4*)&dp[8]  = make_uint4(pkx[4],  pkx[5],  pkx[6],  pkx[7]);
            *(uint4*)&dp[16] = make_uint4(pkx[8],  pkx[9],  pkx[10], pkx[11]);
            *(uint4*)&dp[24] = make_uint4(pkx[12], pkx[13], pkx[14], pkx[15]);
        }
    } else {
        waveStore(pB, nt, 1.f, nullptr, false);
    }
}

// ---------------------------------------------------------------------------
// out = attn @ out_proj_w.T + b.  Same core; A is fp16 (attnb), fp32 stores.
// Grid 256 = 64 mg x 4 nt.
// ---------------------------------------------------------------------------
__global__ __launch_bounds__(256, 2) void out_gemm(
        const u16* __restrict__ attnb, const float* __restrict__ W,
        const float* __restrict__ Wb, float* __restrict__ outf) {
    __shared__ __align__(16) u16 ws[64 * 256];

    const int t    = threadIdx.x;
    const int lane = t & 63;
    const int w    = t >> 6;
    const int il   = lane & 15;
    const int g    = lane >> 4;

    const int logical = (blockIdx.x & 7) * 32 + (blockIdx.x >> 3);
    const int mg = logical >> 2, nt = logical & 3;
    const int m0 = mg * 128, n0 = nt * 64;

    {
        const int kc = (t & 31) * 8, rb_ = t >> 5;
        #pragma unroll
        for (int rr = 0; rr < 8; ++rr) {
            const int row = rb_ * 8 + rr;
            const float* wr = &W[(size_t)(n0 + row) * 256 + kc];
            float4 f0 = *(const float4*)&wr[0];
            float4 f1 = *(const float4*)&wr[4];
            *(uint4*)((char*)ws + row * 512 + ((kc * 2) ^ ((row & 7) << 4))) =
                make_uint4(pk2(f0.x, f0.y), pk2(f0.z, f0.w),
                           pk2(f1.x, f1.y), pk2(f1.z, f1.w));
        }
    }
    half8 bf0[8], bf1[8];
    {
        const u16* a0 = attnb + (size_t)(m0 + w * 32 + il) * 256;
        const u16* a1 = a0 + 16 * 256;
        #pragma unroll
        for (int c = 0; c < 8; ++c) {
            bf0[c] = *(const half8*)&a0[c * 32 + g * 8];
            bf1[c] = *(const half8*)&a1[c * 32 + g * 8];
        }
    }
    __syncthreads();

    f32x4 acc0[4] = {}, acc1[4] = {};
    __builtin_amdgcn_s_setprio(1);
    #pragma unroll
    for (int c = 0; c < 8; ++c) {
        #pragma unroll
        for (int jt = 0; jt < 4; ++jt) {
            const int row = jt * 16 + il;
            half8 af = *(const half8*)((const char*)ws + row * 512 +
                                       ((c * 64 + g * 16) ^ ((row & 7) << 4)));
            acc0[jt] = __builtin_amdgcn_mfma_f32_16x16x32_f16(af, bf0[c], acc0[jt], 0, 0, 0);
            acc1[jt] = __builtin_amdgcn_mfma_f32_16x16x32_f16(af, bf1[c], acc1[jt], 0, 0, 0);
        }
    }
    __builtin_amdgcn_s_setprio(0);

    #pragma unroll
    for (int s = 0; s < 2; ++s) {
        const int m_ = m0 + w * 32 + s * 16 + il;
        float* orow = &outf[(size_t)m_ * 256 + n0];
        #pragma unroll
        for (int jt = 0; jt < 4; ++jt) {
            const f32x4 a = s ? acc1[jt] : acc0[jt];
            *(float4*)&orow[jt * 16 + g * 4] = make_float4(
                a[0] + Wb[n0 + jt * 16 + g * 4 + 0],
                a[1] + Wb[n0 + jt * 16 + g * 4 + 1],
                a[2] + Wb[n0 + jt * 16 + g * 4 + 2],
                a[3] + Wb[n0 + jt * 16 + g * 4 + 3]);
        }
    }
}

// ---------------------------------------------------------------------------
// Fused rel-pos flash attention — EXACT round-3 version (verified 72.4 us).
// ---------------------------------------------------------------------------
__global__ __launch_bounds__(256, 2) void attn_mfma(
        const u16* __restrict__ quB, const u16* __restrict__ qvB,
        const u16* __restrict__ kB,  const u16* __restrict__ vtB,
        const u16* __restrict__ pB,  u16* __restrict__ attn_out) {
    __shared__ __align__(16) u16   k_s[64 * 64];      // [j][d]   8 KB
    __shared__ __align__(16) u16   v_s[64 * 64];      // [d][j]   8 KB
    __shared__ __align__(16) u16   p_s[128 * 64];     // [r][d]  16 KB
    __shared__ __align__(16) float bd_s[4][16 * 84];  // per-wave [il][rr] 21 KB
    __shared__ __align__(16) u16   prob_s[4][16 * 64];// per-wave [il][j]  8 KB

    const int t    = threadIdx.x;
    const int lane = t & 63;
    const int w    = t >> 6;
    const int il   = lane & 15;
    const int g    = lane >> 4;

    const int logical = ((blockIdx.x & 7) << 6) + (blockIdx.x >> 3);
    const int bh = logical >> 5;
    const int i0 = (logical & 31) * 64;
    const int b  = bh >> 2, h = bh & 3;

    half8 qu_f[2], qv_f[2];
    {
        const size_t qrow = ((size_t)bh * L_SEQ + i0 + w * 16 + il) * HD;
        qu_f[0] = *(const half8*)&quB[qrow + g * 8];
        qu_f[1] = *(const half8*)&quB[qrow + 32 + g * 8];
        qv_f[0] = *(const half8*)&qvB[qrow + g * 8];
        qv_f[1] = *(const half8*)&qvB[qrow + 32 + g * 8];
    }

    const int r0w = 48 - 16 * w;
    int krd[4][2], prd[5][2], pbrd[2], pwr[4];
    #pragma unroll
    for (int x4 = 0; x4 < 4; ++x4)
        #pragma unroll
        for (int c = 0; c < 2; ++c) {
            int row = x4 * 16 + il;
            krd[x4][c] = row * 128 + ((c * 64 + g * 16) ^ ((row & 7) << 4));
        }
    #pragma unroll
    for (int rt = 0; rt < 5; ++rt)
        #pragma unroll
        for (int c = 0; c < 2; ++c) {
            int row = r0w + rt * 16 + il;
            prd[rt][c] = row * 128 + ((c * 64 + g * 16) ^ ((row & 7) << 4));
        }
    #pragma unroll
    for (int c = 0; c < 2; ++c)
        pbrd[c] = il * 128 + ((c * 64 + g * 16) ^ ((il & 7) << 4));
    #pragma unroll
    for (int jt = 0; jt < 4; ++jt)
        pwr[jt] = il * 128 + (((jt * 16 + g * 4) * 2) ^ ((il & 7) << 4));
    const int bdwr = il * 84 + g * 4;
    const int bdrd = il * 83 + 15 + g * 4;

    f32x4 outacc[4] = {};
    float m_run = -INFINITY, l_run = 0.f;

    for (int kt = 0; kt < 32; ++kt) {
        const int j0 = kt * 64;
        const int nbase = 1984 - i0 + j0;
        __syncthreads();
        {
            const int rw = t >> 3;
            const int a  = t & 7;
            #pragma unroll
            for (int kr = 0; kr < 2; ++kr) {
                const int j = kr * 32 + rw;
                uint4 val = *(const uint4*)&kB[((size_t)bh * L_SEQ + j0 + j) * HD + a * 8];
                *(uint4*)((char*)k_s + (j * 128 + ((a * 16) ^ ((j & 7) << 4)))) = val;
            }
            #pragma unroll
            for (int vr = 0; vr < 2; ++vr) {
                const int d = vr * 32 + rw;
                uint4 val = *(const uint4*)&vtB[((size_t)bh * HD + d) * L_SEQ + j0 + a * 8];
                *(uint4*)((char*)v_s + (d * 128 + ((a * 16) ^ ((d & 7) << 4)))) = val;
            }
            #pragma unroll
            for (int pr = 0; pr < 4; ++pr) {
                const int r = pr * 32 + rw;
                int n = nbase + r; n = n > (P_ROWS - 1) ? (P_ROWS - 1) : n;
                uint4 val = *(const uint4*)&pB[((size_t)h * P_ROWS + n) * HD + a * 8];
                *(uint4*)((char*)p_s + (r * 128 + ((a * 16) ^ ((r & 7) << 4)))) = val;
            }
        }
        __syncthreads();

        // ---- BD^T band ----
        __builtin_amdgcn_s_setprio(1);
        #pragma unroll
        for (int rt = 0; rt < 5; ++rt) {
            f32x4 acc = {};
            #pragma unroll
            for (int c = 0; c < 2; ++c) {
                half8 a = *(const half8*)((const char*)p_s + prd[rt][c]);
                acc = __builtin_amdgcn_mfma_f32_16x16x32_f16(a, qv_f[c], acc, 0, 0, 0);
            }
            *(f32x4*)&bd_s[w][bdwr + rt * 16] = acc;
        }
        __builtin_amdgcn_s_setprio(0);

        // ---- AC (S^T) + rel-shift combine ----
        float sreg[16];
        __builtin_amdgcn_s_setprio(1);
        #pragma unroll
        for (int jt = 0; jt < 4; ++jt) {
            f32x4 acc = {};
            #pragma unroll
            for (int c = 0; c < 2; ++c) {
                half8 a = *(const half8*)((const char*)k_s + krd[jt][c]);
                acc = __builtin_amdgcn_mfma_f32_16x16x32_f16(a, qu_f[c], acc, 0, 0, 0);
            }
            #pragma unroll
            for (int tt = 0; tt < 4; ++tt)
                sreg[jt * 4 + tt] = acc[tt] + bd_s[w][bdrd + jt * 16 + tt];
        }
        __builtin_amdgcn_s_setprio(0);

        // ---- online softmax ----
        float mx = sreg[0];
        #pragma unroll
        for (int z = 1; z < 16; ++z) mx = fmaxf(mx, sreg[z]);
        mx = fmaxf(mx, __shfl_xor(mx, 16));
        mx = fmaxf(mx, __shfl_xor(mx, 32));
        const float m_new = fmaxf(m_run, mx);
        const float corr = __expf(m_run - m_new);
        float lsum = 0.f;
        #pragma unroll
        for (int z = 0; z < 16; ++z) { sreg[z] = __expf(sreg[z] - m_new); lsum += sreg[z]; }
        lsum += __shfl_xor(lsum, 16);
        lsum += __shfl_xor(lsum, 32);
        l_run = l_run * corr + lsum;
        m_run = m_new;
        #pragma unroll
        for (int dt = 0; dt < 4; ++dt) outacc[dt] *= corr;

        // ---- pack probabilities ----
        #pragma unroll
        for (int jt = 0; jt < 4; ++jt) {
            u32 lo = pk2(sreg[jt * 4 + 0], sreg[jt * 4 + 1]);
            u32 hi = pk2(sreg[jt * 4 + 2], sreg[jt * 4 + 3]);
            *(uint2*)((char*)&prob_s[w][0] + pwr[jt]) = make_uint2(lo, hi);
        }

        // ---- PV ----
        half8 pfrag[2];
        #pragma unroll
        for (int c = 0; c < 2; ++c)
            pfrag[c] = *(const half8*)((const char*)&prob_s[w][0] + pbrd[c]);
        __builtin_amdgcn_s_setprio(1);
        #pragma unroll
        for (int dt = 0; dt < 4; ++dt) {
            #pragma unroll
            for (int c = 0; c < 2; ++c) {
                half8 a = *(const half8*)((const char*)v_s + krd[dt][c]);
                outacc[dt] = __builtin_amdgcn_mfma_f32_16x16x32_f16(a, pfrag[c], outacc[dt], 0, 0, 0);
            }
        }
        __builtin_amdgcn_s_setprio(0);
    }

    // ---- epilogue: fp16 [m][e] ----
    const float inv = 1.f / l_run;
    const int m = (i0 + w * 16 + il) * NB + b;
    u16* orow = &attn_out[(size_t)m * EMB + h * HD];
    #pragma unroll
    for (int dt = 0; dt < 4; ++dt) {
        u32 lo = pk2(outacc[dt][0] * inv, outacc[dt][1] * inv);
        u32 hi = pk2(outacc[dt][2] * inv, outacc[dt][3] * inv);
        *(uint2*)&orow[dt * 16 + g * 4] = make_uint2(lo, hi);
    }
}

// ---------------------------------------------------------------------------
extern "C" void kernel_launch(void* const* d_in, const int* in_sizes, int n_in,
                              void* d_out, int out_size, void* d_ws, size_t ws_size,
                              hipStream_t stream) {
    const float* x        = (const float*)d_in[0];
    const float* pos_emb  = (const float*)d_in[1];
    const float* in_w     = (const float*)d_in[2];
    const float* in_b     = (const float*)d_in[3];
    const float* pos_w    = (const float*)d_in[4];
    const float* u_bias   = (const float*)d_in[5];
    const float* v_bias   = (const float*)d_in[6];
    const float* out_w    = (const float*)d_in[7];
    const float* out_b    = (const float*)d_in[8];
    float* out = (float*)d_out;

    // fp16 workspace (~23 MB)
    u16* quB   = (u16*)d_ws;
    u16* qvB   = quB + (size_t)16 * L_SEQ * HD;
    u16* kB    = qvB + (size_t)16 * L_SEQ * HD;
    u16* vtB   = kB  + (size_t)16 * L_SEQ * HD;
    u16* pB    = vtB + (size_t)16 * L_SEQ * HD;
    u16* attnb = pB  + (size_t)NH * P_ROWS * HD;

    qkvpos_gemm<<<dim3(896), 256, 0, stream>>>(
        x, pos_emb, in_w, in_b, pos_w, u_bias, v_bias, quB, qvB, kB, vtB, pB);
    attn_mfma<<<dim3(512), 256, 0, stream>>>(quB, qvB, kB, vtB, pB, attnb);
    out_gemm<<<dim3(256), 256, 0, stream>>>(attnb, out_w, out_b, out);
}